// Round 17
// baseline (1198.553 us; speedup 1.0000x reference)
//
#include <hip/hip_runtime.h>
#include <cstdint>
#include <cstddef>

typedef __attribute__((ext_vector_type(8))) __bf16 bf16x8;
typedef __attribute__((ext_vector_type(8))) unsigned short u16x8;
typedef __attribute__((ext_vector_type(4))) unsigned short u16x4;
typedef __attribute__((ext_vector_type(2))) unsigned short u16x2;
typedef __attribute__((ext_vector_type(4))) float f32x4;
typedef __attribute__((ext_vector_type(2))) float f32x2;

// ---- helpers -------------------------------------------------------------
__device__ __forceinline__ unsigned short f2bf(float f){
  unsigned int u = __float_as_uint(f);
  u += 0x7FFFu + ((u >> 16) & 1u);          // round to nearest even
  return (unsigned short)(u >> 16);
}
__device__ __forceinline__ float bf2f(unsigned short s){
  return __uint_as_float(((unsigned int)s) << 16);
}
__device__ __forceinline__ float sigm(float x){ return 1.f/(1.f + __expf(-x)); }
__device__ __forceinline__ float tanh_f(float x){ float e = __expf(2.f*x); return 1.f - 2.f/(e + 1.f); }
__device__ __forceinline__ f32x4 mfma16(u16x8 a, u16x8 b, f32x4 c){
  return __builtin_amdgcn_mfma_f32_16x16x32_bf16(
      __builtin_bit_cast(bf16x8, a), __builtin_bit_cast(bf16x8, b), c, 0, 0, 0);
}

// B=1024, T=128, F=128, H=256
// seq14 = seq13 (round 16, 734us, verified) + NON-TEMPORAL streaming loads.
//   Round-16 null (2 vs 4 waves/SIMD identical) proved the stream is
//   throughput-bound at ~31 B/cy/CU — exactly half the 64 B/cy TCP fill.
//   Hypothesis: 416 KB/step of zero-reuse loads thrash the 32 KB L1
//   (read-allocate overhead halves fill). nt loads bypass L1 allocation.

__device__ __forceinline__ float wcval(int g, int n, int k,
    const float* __restrict__ Wih, const float* __restrict__ Whh){
  if (g==0) return Wih[n*512 + 128+k]       + Whh[n*256 + k];
  if (g==1) return Wih[(256+n)*512 + 128+k] + Whh[(256+n)*256 + k];
  if (g==2) return Wih[(512+n)*512 + 128+k];
  return Whh[(512+n)*256 + k];
}

// ---- weight prep (unchanged from round 16) -------------------------------
// WstrG: (((w*6+s)*4+g)*64+l)*8+j  w=0..15, s=0..5 -> ks=[0,1,2,3,6,7][s],
//        n=w*16+(l&15)                                (196608 elems, 384 KB)
// WldsG: ((w*8+g*2+ks2)*64+l)*8+j  ks=4+ks2           ( 65536 elems, 128 KB)
// W2  : [nt(48)][ks(8)][lane(64)][8] ; Wd : [nt(16)][ks(4)][lane(64)][8]
__global__ __launch_bounds__(256) void kw(
    const float* __restrict__ Wdh, const float* __restrict__ Wih,
    const float* __restrict__ Whh, const float* __restrict__ bih,
    const float* __restrict__ bhh,
    unsigned short* __restrict__ WstrG, unsigned short* __restrict__ WldsG,
    unsigned short* __restrict__ W2,
    unsigned short* __restrict__ Wd, float* __restrict__ b2){
  int i0 = blockIdx.x*256 + threadIdx.x;
  int stride = gridDim.x*256;
  for (int idx=i0; idx<196608; idx+=stride){          // WstrG (ks 0..3,6,7)
    int j=idx&7, l=(idx>>3)&63, r=idx>>9;             // r < 384
    int g=r&3, r2=r>>2;                               // r2 = w*6+s
    int s=r2%6, w=r2/6;
    int ks = (s<4) ? s : (s+2);
    int n = w*16 + (l&15);
    int k = ks*32 + ((l>>4)<<3) + j;
    WstrG[idx] = f2bf(wcval(g, n, k, Wih, Whh));
  }
  for (int idx=i0; idx<65536; idx+=stride){           // WldsG (ks 4..5)
    int j=idx&7, l=(idx>>3)&63, r=idx>>9;             // r < 128
    int ks2=r&1, g=(r>>1)&3, w=r>>3;
    int n = w*16 + (l&15);
    int k = (4+ks2)*32 + ((l>>4)<<3) + j;
    WldsG[idx] = f2bf(wcval(g, n, k, Wih, Whh));
  }
  for (int idx=i0; idx<196608; idx+=stride){
    int j=idx&7, l=(idx>>3)&63, ks=(idx>>9)&7, nt=idx>>12;
    int n = nt*16 + (l&15);
    int k = ks*32 + ((l>>4)<<3) + j;
    float v = (k<128) ? Wih[n*512 + k] : Wih[n*512 + 256 + k];
    W2[idx] = f2bf(v);
  }
  for (int idx=i0; idx<32768; idx+=stride){
    int j=idx&7, l=(idx>>3)&63, ks=(idx>>9)&3, nt=idx>>11;
    int n = nt*16 + (l&15);
    int k = ks*32 + ((l>>4)<<3) + j;
    Wd[idx] = f2bf(Wdh[n*128 + k]);
  }
  for (int idx=i0; idx<768; idx+=stride)
    b2[idx] = bih[idx] + (idx<512 ? bhh[idx] : 0.f);
}

// ---- elementwise prep (unchanged, verified) ------------------------------
__global__ __launch_bounds__(256) void kprep(
    const float* __restrict__ X, const float* __restrict__ M,
    const float* __restrict__ D, const float* __restrict__ mu,
    const float* __restrict__ Xl, const float* __restrict__ Wdx,
    const float* __restrict__ bdx,
    unsigned short* __restrict__ Apre, unsigned short* __restrict__ Dt){
  int lane = threadIdx.x & 63;
  int wave = (blockIdx.x*256 + threadIdx.x) >> 6;
  int c0 = lane*2;
  float dg0 = Wdx[c0*128 + c0];
  float dg1 = Wdx[(c0+1)*128 + (c0+1)];
  float bx0 = bdx[c0], bx1 = bdx[c0+1];
  for (int r = wave; r < 131072; r += 4096){
    int t = r>>10, b = r&1023;
    size_t src = ((size_t)b*128 + t)*128 + c0;
    f32x2 x  = *(const f32x2*)(X+src);
    f32x2 m  = *(const f32x2*)(M+src);
    f32x2 d  = *(const f32x2*)(D+src);
    f32x2 xl = *(const f32x2*)(Xl+src);
    f32x2 mb = *(const f32x2*)(mu + b*128 + c0);
    float g0 = __expf(-fmaxf(0.f, d.x*dg0 + bx0));
    float g1 = __expf(-fmaxf(0.f, d.y*dg1 + bx1));
    float xh0 = g0*xl.x + (1.f-g0)*mb.x;
    float xh1 = g1*xl.y + (1.f-g1)*mb.y;
    float xi0 = m.x*x.x + (1.f-m.x)*xh0;
    float xi1 = m.y*x.y + (1.f-m.y)*xh1;
    size_t ar = (size_t)r*256;
    *(u16x2*)(Apre + ar + c0)        = u16x2{f2bf(xi0), f2bf(xi1)};
    *(u16x2*)(Apre + ar + 128 + c0)  = u16x2{f2bf(m.x), f2bf(m.y)};
    *(u16x2*)(Dt + (size_t)r*128 + c0) = u16x2{f2bf(d.x), f2bf(d.y)};
  }
}

// ---- LDS-staged activation GEMM (unchanged from round 15, verified) ------
template<int KS, int NTOT, int PNT, int MODE>
__global__ __launch_bounds__(512) void gemm_lds(
    const unsigned short* __restrict__ A, const unsigned short* __restrict__ Bw,
    const float* __restrict__ bias, unsigned short* __restrict__ out){
  extern __shared__ char smem[];
  unsigned short* Bs = (unsigned short*)smem;       // 65536 B
  const int N = NTOT*16;
  const int lane = threadIdx.x & 63;
  const int w    = threadIdx.x >> 6;
  const size_t rb = (size_t)blockIdx.x*128 + w*16;
  const int lr = lane&15, lk=(lane>>4)<<3, lq=(lane>>4)<<2;
  u16x8 a[KS];
  #pragma unroll
  for (int ks=0; ks<KS; ++ks)
    a[ks] = *(const u16x8*)&A[(rb + lr)*(KS*32) + ks*32 + lk];
  #pragma unroll
  for (int p=0; p<NTOT/PNT; ++p){
    __syncthreads();
    {
      const u16x8* src = (const u16x8*)&Bw[(size_t)p*PNT*KS*512];
      u16x8* dst = (u16x8*)Bs;
      #pragma unroll
      for (int i=0; i<8; ++i)
        dst[threadIdx.x + i*512] = src[threadIdx.x + i*512];
    }
    __syncthreads();
    f32x4 acc[PNT];
    #pragma unroll
    for (int i=0; i<PNT; ++i) acc[i] = f32x4{0.f,0.f,0.f,0.f};
    #pragma unroll
    for (int ks=0; ks<KS; ++ks)
      #pragma unroll
      for (int i=0; i<PNT; ++i){
        u16x8 b = *(const u16x8*)&Bs[((i*KS + ks)*64 + lane)*8];
        acc[i] = mfma16(a[ks], b, acc[i]);
      }
    #pragma unroll
    for (int i=0; i<PNT; ++i){
      int col = (p*PNT + i)*16 + lr;
      float bv = bias[col];
      #pragma unroll
      for (int q=0; q<4; ++q){
        float v = acc[i][q] + bv;
        if (MODE==1) v = __expf(-fmaxf(0.f, v));
        out[(rb + lq + q)*(size_t)N + col] = f2bf(v);
      }
    }
  }
}

// ---- persistent sequential kernel: 16 waves, nt-pipelined stream ---------
__global__ __launch_bounds__(1024) void seq14(
    const unsigned short* __restrict__ WstrG, const unsigned short* __restrict__ WldsG,
    const unsigned short* __restrict__ gamma, const unsigned short* __restrict__ gipre,
    const float* __restrict__ bhh, float* __restrict__ out){
  extern __shared__ char smem[];
  unsigned short* Wlds = (unsigned short*)smem;            // 131072 B (ks4,5)
  unsigned short* hsw  = (unsigned short*)(smem + 131072); //   8192 B
  const int tid  = threadIdx.x;
  const int lane = tid & 63;
  const int w    = tid >> 6;              // 0..15
  const int bbase = blockIdx.x * 16;
  const int lr   = lane & 15;
  const int lq4  = (lane >> 4) << 2;
  const int col  = w*16 + lr;             // 0..255

  // ---- prologue: LDS-resident ks4..5 (128 KB) ----
  for (int i = tid; i < 8192; i += 1024)
    *(u16x8*)&Wlds[i*8] = *(const u16x8*)&WldsG[i*8];

  float h_reg[4];
  #pragma unroll
  for (int q=0; q<4; ++q) h_reg[q] = 0.f;
  const float bnn = bhh[512 + col];

  int sh[4];
  #pragma unroll
  for (int q=0; q<4; ++q)
    sh[q] = (col>>5)*512 + ((lq4+q) + (((col>>3)&3)<<4))*8 + (col&7);

  unsigned short g_pre[4];
  #pragma unroll
  for (int q=0; q<4; ++q)
    g_pre[q] = gamma[((size_t)(bbase + lq4 + q))*256 + col];

  const unsigned short* wsb = WstrG + (size_t)w*12288 + lane*8;

  __syncthreads();

  for (int t = 0; t < 128; ++t){
    // ---- phase 1: decay h, publish A-fragments ----
    #pragma unroll
    for (int q=0; q<4; ++q){
      float hd = h_reg[q] * bf2f(g_pre[q]);
      h_reg[q] = hd;
      hsw[sh[q]] = f2bf(hd);
    }
    __syncthreads();   // S1: hsw ready

    // rep stores AFTER the barrier: drain overlaps the MFMA phase
    #pragma unroll
    for (int q=0; q<4; ++q)
      out[((size_t)(bbase+lq4+q)*128 + t)*256 + col] = h_reg[q];

    f32x4 acc[4];
    #pragma unroll
    for (int g=0; g<4; ++g) acc[g] = f32x4{0.f,0.f,0.f,0.f};

    // opaque per-iteration offset: keeps stream loads in-loop, in order
    int off = 0;
    asm volatile("" : "+v"(off));
    const unsigned short* wp = wsb + off;

    u16x8 r0[4], r1[4], r2[4];
    // NON-TEMPORAL issue: bypass L1 allocation (zero-reuse stream)
    #define ISS(r_, s_) { \
      _Pragma("unroll") \
      for (int i=0;i<4;++i) \
        r_[i] = __builtin_nontemporal_load((const u16x8*)(wp + ((s_)*4+i)*512)); \
      } __builtin_amdgcn_sched_barrier(0);
    #define CONS(r_, ks_) { \
      u16x8 aR = *(const u16x8*)&hsw[(ks_)*512 + lane*8]; \
      _Pragma("unroll") \
      for (int i=0;i<4;++i) acc[i] = mfma16(aR, r_[i], acc[i]); \
      } __builtin_amdgcn_sched_barrier(0);

    ISS(r0,0) ISS(r1,1) ISS(r2,2)          // 12 chunks in flight
    CONS(r0,0) ISS(r0,3)
    CONS(r1,1) ISS(r1,4)
    CONS(r2,2) ISS(r2,5)

    // gate-input prefetch under batch-flight cover (nt: read-once data)
    const unsigned short* gp = gipre + ((size_t)t*1024 + bbase)*768;
    unsigned short gv[3][4];
    #pragma unroll
    for (int g3=0; g3<3; ++g3)
      #pragma unroll
      for (int q=0; q<4; ++q)
        gv[g3][q] = __builtin_nontemporal_load(
            gp + (size_t)(lq4+q)*768 + g3*256 + col);
    if (t < 127){
      #pragma unroll
      for (int q=0; q<4; ++q)
        g_pre[q] = __builtin_nontemporal_load(
            gamma + ((size_t)(t+1)*1024 + bbase + lq4 + q)*256 + col);
    }
    __builtin_amdgcn_sched_barrier(0);

    CONS(r0,3)
    // LDS-resident ks4..5 (8 MFMA) — covers tail of batches 4,5
    #pragma unroll
    for (int ks2=0; ks2<2; ++ks2){
      u16x8 aL = *(const u16x8*)&hsw[(4+ks2)*512 + lane*8];
      #pragma unroll
      for (int g=0; g<4; ++g){
        u16x8 bL = *(const u16x8*)&Wlds[((w*8 + g*2 + ks2)*64 + lane)*8];
        acc[g] = mfma16(aL, bL, acc[g]);
      }
    }
    __builtin_amdgcn_sched_barrier(0);
    CONS(r1,6)
    CONS(r2,7)
    #undef ISS
    #undef CONS
    __syncthreads();   // S2: hsw reads done -> next phase1 may overwrite

    // ---- gate phase (in-register) ----
    #pragma unroll
    for (int q=0; q<4; ++q){
      float gr = bf2f(gv[0][q]);
      float gz = bf2f(gv[1][q]);
      float gn = bf2f(gv[2][q]);
      float rr = sigm(gr + acc[0][q]);
      float zz = sigm(gz + acc[1][q]);
      float nv = tanh_f(gn + acc[2][q] + rr*(acc[3][q] + bnn));
      float hn = (1.f-zz)*nv + zz*h_reg[q];
      h_reg[q] = hn;
      if (t == 127) out[(size_t)33554432 + (size_t)(bbase+lq4+q)*256 + col] = hn;
    }
  }
}

// ---- host glue -----------------------------------------------------------
extern "C" void kernel_launch(void* const* d_in, const int* in_sizes, int n_in,
                              void* d_out, int out_size, void* d_ws, size_t ws_size,
                              hipStream_t stream){
  (void)in_sizes; (void)n_in; (void)out_size; (void)ws_size;
  const float* X   = (const float*)d_in[0];
  const float* M   = (const float*)d_in[1];
  const float* D   = (const float*)d_in[2];
  const float* mu  = (const float*)d_in[3];
  const float* Xl  = (const float*)d_in[4];
  const float* Wdh = (const float*)d_in[5];
  const float* bdh = (const float*)d_in[6];
  const float* Wdx = (const float*)d_in[7];
  const float* bdx = (const float*)d_in[8];
  const float* Wih = (const float*)d_in[9];
  const float* Whh = (const float*)d_in[10];
  const float* bih = (const float*)d_in[11];
  const float* bhh = (const float*)d_in[12];
  float* out = (float*)d_out;
  char* ws = (char*)d_ws;

  // workspace layout
  unsigned short* gipre = (unsigned short*)ws;                      // 201326592 B
  unsigned short* gamma = (unsigned short*)(ws + 201326592);        //  67108864 B
  unsigned short* W2sw  = (unsigned short*)(ws + 268435456);        //    393216 B
  unsigned short* Wdsw  = (unsigned short*)(ws + 268828672);        //     65536 B
  unsigned short* WstrG = (unsigned short*)(ws + 268894208);        //    393216 B
  unsigned short* WldsG = (unsigned short*)(ws + 269287424);        //    131072 B
  float*          b2    = (float*)        (ws + 269418496);         //      3072 B
  // Apre (67.1MB) + Dt (33.6MB) staged inside d_out: fully consumed by the
  // GEMMs below BEFORE seq14 writes the real outputs (same-stream ordering).
  unsigned short* Apre = (unsigned short*)d_out;
  unsigned short* Dt   = (unsigned short*)((char*)d_out + 67108864);

  hipFuncSetAttribute(reinterpret_cast<const void*>(seq14),
                      hipFuncAttributeMaxDynamicSharedMemorySize, 139264);
  hipFuncSetAttribute(reinterpret_cast<const void*>(&gemm_lds<4,16,16,1>),
                      hipFuncAttributeMaxDynamicSharedMemorySize, 65536);
  hipFuncSetAttribute(reinterpret_cast<const void*>(&gemm_lds<8,48,8,0>),
                      hipFuncAttributeMaxDynamicSharedMemorySize, 65536);

  kw<<<256, 256, 0, stream>>>(Wdh, Wih, Whh, bih, bhh, WstrG, WldsG, W2sw, Wdsw, b2);
  kprep<<<1024, 256, 0, stream>>>(X, M, D, mu, Xl, Wdx, bdx, Apre, Dt);
  gemm_lds<4,16,16,1><<<1024, 512, 65536, stream>>>(Dt, Wdsw, bdh, gamma);
  gemm_lds<8,48,8,0><<<1024, 512, 65536, stream>>>(Apre, W2sw, b2, gipre);
  seq14<<<64, 1024, 139264, stream>>>(WstrG, WldsG, gamma, gipre, bhh, out);
}

// Round 18
// 940.131 us; speedup vs baseline: 1.2749x; 1.2749x over previous
//
#include <hip/hip_runtime.h>
#include <cstdint>
#include <cstddef>

typedef __attribute__((ext_vector_type(8))) __bf16 bf16x8;
typedef __attribute__((ext_vector_type(8))) unsigned short u16x8;
typedef __attribute__((ext_vector_type(4))) unsigned short u16x4;
typedef __attribute__((ext_vector_type(2))) unsigned short u16x2;
typedef __attribute__((ext_vector_type(4))) float f32x4;
typedef __attribute__((ext_vector_type(2))) float f32x2;

// ---- helpers -------------------------------------------------------------
__device__ __forceinline__ unsigned short f2bf(float f){
  unsigned int u = __float_as_uint(f);
  u += 0x7FFFu + ((u >> 16) & 1u);          // round to nearest even
  return (unsigned short)(u >> 16);
}
__device__ __forceinline__ float bf2f(unsigned short s){
  return __uint_as_float(((unsigned int)s) << 16);
}
__device__ __forceinline__ float sigm(float x){ return 1.f/(1.f + __expf(-x)); }
__device__ __forceinline__ float tanh_f(float x){ float e = __expf(2.f*x); return 1.f - 2.f/(e + 1.f); }
__device__ __forceinline__ f32x4 mfma16(u16x8 a, u16x8 b, f32x4 c){
  return __builtin_amdgcn_mfma_f32_16x16x32_bf16(
      __builtin_bit_cast(bf16x8, a), __builtin_bit_cast(bf16x8, b), c, 0, 0, 0);
}

// B=1024, T=128, F=128, H=256
// seq15 = seq13 (round 16, 734us, verified) + XCD-stagger:
//   Round-17: nt loads broke L2 residency (FETCH 133->246MB, 734->1030us).
//   Round-16: occupancy doubling was null -> stream throughput-bound at
//   ~31 B/cy/CU. Hypothesis: all 8 CUs of an XCD read the SAME 384 KB
//   weight lines in the SAME order -> same-line L2 bank serialization
//   (256 B/cy bank / 8 CUs = 32 B/cy, matches). Fix: rotate each WG's
//   batch order by (bid>>3)%6 so co-XCD CUs read disjoint regions at any
//   instant. s is wave-uniform -> scalar; pipeline structure unchanged.

__device__ __forceinline__ float wcval(int g, int n, int k,
    const float* __restrict__ Wih, const float* __restrict__ Whh){
  if (g==0) return Wih[n*512 + 128+k]       + Whh[n*256 + k];
  if (g==1) return Wih[(256+n)*512 + 128+k] + Whh[(256+n)*256 + k];
  if (g==2) return Wih[(512+n)*512 + 128+k];
  return Whh[(512+n)*256 + k];
}

// ---- weight prep (unchanged from round 16) -------------------------------
// WstrG: (((w*6+s)*4+g)*64+l)*8+j  w=0..15, s=0..5 -> ks=[0,1,2,3,6,7][s],
//        n=w*16+(l&15)                                (196608 elems, 384 KB)
// WldsG: ((w*8+g*2+ks2)*64+l)*8+j  ks=4+ks2           ( 65536 elems, 128 KB)
// W2  : [nt(48)][ks(8)][lane(64)][8] ; Wd : [nt(16)][ks(4)][lane(64)][8]
__global__ __launch_bounds__(256) void kw(
    const float* __restrict__ Wdh, const float* __restrict__ Wih,
    const float* __restrict__ Whh, const float* __restrict__ bih,
    const float* __restrict__ bhh,
    unsigned short* __restrict__ WstrG, unsigned short* __restrict__ WldsG,
    unsigned short* __restrict__ W2,
    unsigned short* __restrict__ Wd, float* __restrict__ b2){
  int i0 = blockIdx.x*256 + threadIdx.x;
  int stride = gridDim.x*256;
  for (int idx=i0; idx<196608; idx+=stride){          // WstrG (ks 0..3,6,7)
    int j=idx&7, l=(idx>>3)&63, r=idx>>9;             // r < 384
    int g=r&3, r2=r>>2;                               // r2 = w*6+s
    int s=r2%6, w=r2/6;
    int ks = (s<4) ? s : (s+2);
    int n = w*16 + (l&15);
    int k = ks*32 + ((l>>4)<<3) + j;
    WstrG[idx] = f2bf(wcval(g, n, k, Wih, Whh));
  }
  for (int idx=i0; idx<65536; idx+=stride){           // WldsG (ks 4..5)
    int j=idx&7, l=(idx>>3)&63, r=idx>>9;             // r < 128
    int ks2=r&1, g=(r>>1)&3, w=r>>3;
    int n = w*16 + (l&15);
    int k = (4+ks2)*32 + ((l>>4)<<3) + j;
    WldsG[idx] = f2bf(wcval(g, n, k, Wih, Whh));
  }
  for (int idx=i0; idx<196608; idx+=stride){
    int j=idx&7, l=(idx>>3)&63, ks=(idx>>9)&7, nt=idx>>12;
    int n = nt*16 + (l&15);
    int k = ks*32 + ((l>>4)<<3) + j;
    float v = (k<128) ? Wih[n*512 + k] : Wih[n*512 + 256 + k];
    W2[idx] = f2bf(v);
  }
  for (int idx=i0; idx<32768; idx+=stride){
    int j=idx&7, l=(idx>>3)&63, ks=(idx>>9)&3, nt=idx>>11;
    int n = nt*16 + (l&15);
    int k = ks*32 + ((l>>4)<<3) + j;
    Wd[idx] = f2bf(Wdh[n*128 + k]);
  }
  for (int idx=i0; idx<768; idx+=stride)
    b2[idx] = bih[idx] + (idx<512 ? bhh[idx] : 0.f);
}

// ---- elementwise prep (unchanged, verified) ------------------------------
__global__ __launch_bounds__(256) void kprep(
    const float* __restrict__ X, const float* __restrict__ M,
    const float* __restrict__ D, const float* __restrict__ mu,
    const float* __restrict__ Xl, const float* __restrict__ Wdx,
    const float* __restrict__ bdx,
    unsigned short* __restrict__ Apre, unsigned short* __restrict__ Dt){
  int lane = threadIdx.x & 63;
  int wave = (blockIdx.x*256 + threadIdx.x) >> 6;
  int c0 = lane*2;
  float dg0 = Wdx[c0*128 + c0];
  float dg1 = Wdx[(c0+1)*128 + (c0+1)];
  float bx0 = bdx[c0], bx1 = bdx[c0+1];
  for (int r = wave; r < 131072; r += 4096){
    int t = r>>10, b = r&1023;
    size_t src = ((size_t)b*128 + t)*128 + c0;
    f32x2 x  = *(const f32x2*)(X+src);
    f32x2 m  = *(const f32x2*)(M+src);
    f32x2 d  = *(const f32x2*)(D+src);
    f32x2 xl = *(const f32x2*)(Xl+src);
    f32x2 mb = *(const f32x2*)(mu + b*128 + c0);
    float g0 = __expf(-fmaxf(0.f, d.x*dg0 + bx0));
    float g1 = __expf(-fmaxf(0.f, d.y*dg1 + bx1));
    float xh0 = g0*xl.x + (1.f-g0)*mb.x;
    float xh1 = g1*xl.y + (1.f-g1)*mb.y;
    float xi0 = m.x*x.x + (1.f-m.x)*xh0;
    float xi1 = m.y*x.y + (1.f-m.y)*xh1;
    size_t ar = (size_t)r*256;
    *(u16x2*)(Apre + ar + c0)        = u16x2{f2bf(xi0), f2bf(xi1)};
    *(u16x2*)(Apre + ar + 128 + c0)  = u16x2{f2bf(m.x), f2bf(m.y)};
    *(u16x2*)(Dt + (size_t)r*128 + c0) = u16x2{f2bf(d.x), f2bf(d.y)};
  }
}

// ---- LDS-staged activation GEMM (unchanged from round 15, verified) ------
template<int KS, int NTOT, int PNT, int MODE>
__global__ __launch_bounds__(512) void gemm_lds(
    const unsigned short* __restrict__ A, const unsigned short* __restrict__ Bw,
    const float* __restrict__ bias, unsigned short* __restrict__ out){
  extern __shared__ char smem[];
  unsigned short* Bs = (unsigned short*)smem;       // 65536 B
  const int N = NTOT*16;
  const int lane = threadIdx.x & 63;
  const int w    = threadIdx.x >> 6;
  const size_t rb = (size_t)blockIdx.x*128 + w*16;
  const int lr = lane&15, lk=(lane>>4)<<3, lq=(lane>>4)<<2;
  u16x8 a[KS];
  #pragma unroll
  for (int ks=0; ks<KS; ++ks)
    a[ks] = *(const u16x8*)&A[(rb + lr)*(KS*32) + ks*32 + lk];
  #pragma unroll
  for (int p=0; p<NTOT/PNT; ++p){
    __syncthreads();
    {
      const u16x8* src = (const u16x8*)&Bw[(size_t)p*PNT*KS*512];
      u16x8* dst = (u16x8*)Bs;
      #pragma unroll
      for (int i=0; i<8; ++i)
        dst[threadIdx.x + i*512] = src[threadIdx.x + i*512];
    }
    __syncthreads();
    f32x4 acc[PNT];
    #pragma unroll
    for (int i=0; i<PNT; ++i) acc[i] = f32x4{0.f,0.f,0.f,0.f};
    #pragma unroll
    for (int ks=0; ks<KS; ++ks)
      #pragma unroll
      for (int i=0; i<PNT; ++i){
        u16x8 b = *(const u16x8*)&Bs[((i*KS + ks)*64 + lane)*8];
        acc[i] = mfma16(a[ks], b, acc[i]);
      }
    #pragma unroll
    for (int i=0; i<PNT; ++i){
      int col = (p*PNT + i)*16 + lr;
      float bv = bias[col];
      #pragma unroll
      for (int q=0; q<4; ++q){
        float v = acc[i][q] + bv;
        if (MODE==1) v = __expf(-fmaxf(0.f, v));
        out[(rb + lq + q)*(size_t)N + col] = f2bf(v);
      }
    }
  }
}

// ---- persistent sequential kernel: 16 waves, XCD-staggered stream --------
__global__ __launch_bounds__(1024) void seq15(
    const unsigned short* __restrict__ WstrG, const unsigned short* __restrict__ WldsG,
    const unsigned short* __restrict__ gamma, const unsigned short* __restrict__ gipre,
    const float* __restrict__ bhh, float* __restrict__ out){
  extern __shared__ char smem[];
  unsigned short* Wlds = (unsigned short*)smem;            // 131072 B (ks4,5)
  unsigned short* hsw  = (unsigned short*)(smem + 131072); //   8192 B
  const int tid  = threadIdx.x;
  const int lane = tid & 63;
  const int w    = tid >> 6;              // 0..15
  const int bbase = blockIdx.x * 16;
  const int lr   = lane & 15;
  const int lq4  = (lane >> 4) << 2;
  const int col  = w*16 + lr;             // 0..255

  // batch rotation: WGs sharing an XCD (bid%8 equal) have distinct bid>>3
  const int rot = (int)(blockIdx.x >> 3) % 6;
  int sv[6];
  #pragma unroll
  for (int i=0; i<6; ++i){ int s = rot + i; sv[i] = (s >= 6) ? s - 6 : s; }
  // ks for batch s: [0,1,2,3,6,7][s] = s + 2*(s>=4)
  int kv[6];
  #pragma unroll
  for (int i=0; i<6; ++i) kv[i] = sv[i] + (((sv[i] >> 2) & 1) << 1);

  // ---- prologue: LDS-resident ks4..5 (128 KB) ----
  for (int i = tid; i < 8192; i += 1024)
    *(u16x8*)&Wlds[i*8] = *(const u16x8*)&WldsG[i*8];

  float h_reg[4];
  #pragma unroll
  for (int q=0; q<4; ++q) h_reg[q] = 0.f;
  const float bnn = bhh[512 + col];

  int sh[4];
  #pragma unroll
  for (int q=0; q<4; ++q)
    sh[q] = (col>>5)*512 + ((lq4+q) + (((col>>3)&3)<<4))*8 + (col&7);

  unsigned short g_pre[4];
  #pragma unroll
  for (int q=0; q<4; ++q)
    g_pre[q] = gamma[((size_t)(bbase + lq4 + q))*256 + col];

  const unsigned short* wsb = WstrG + (size_t)w*12288 + lane*8;

  __syncthreads();

  for (int t = 0; t < 128; ++t){
    // ---- phase 1: decay h, publish A-fragments ----
    #pragma unroll
    for (int q=0; q<4; ++q){
      float hd = h_reg[q] * bf2f(g_pre[q]);
      h_reg[q] = hd;
      hsw[sh[q]] = f2bf(hd);
    }
    __syncthreads();   // S1: hsw ready

    // rep stores AFTER the barrier: drain overlaps the MFMA phase
    #pragma unroll
    for (int q=0; q<4; ++q)
      out[((size_t)(bbase+lq4+q)*128 + t)*256 + col] = h_reg[q];

    f32x4 acc[4];
    #pragma unroll
    for (int g=0; g<4; ++g) acc[g] = f32x4{0.f,0.f,0.f,0.f};

    // opaque per-iteration offset: keeps stream loads in-loop, in order
    int off = 0;
    asm volatile("" : "+v"(off));
    const unsigned short* wp = wsb + off;

    u16x8 r0[4], r1[4], r2[4];
    #define ISS(r_, s_) { \
      _Pragma("unroll") \
      for (int i=0;i<4;++i) r_[i] = *(const u16x8*)(wp + ((s_)*4+i)*512); \
      } __builtin_amdgcn_sched_barrier(0);
    #define CONS(r_, k_) { \
      u16x8 aR = *(const u16x8*)&hsw[(k_)*512 + lane*8]; \
      _Pragma("unroll") \
      for (int i=0;i<4;++i) acc[i] = mfma16(aR, r_[i], acc[i]); \
      } __builtin_amdgcn_sched_barrier(0);

    ISS(r0,sv[0]) ISS(r1,sv[1]) ISS(r2,sv[2])      // 12 chunks in flight
    CONS(r0,kv[0]) ISS(r0,sv[3])
    CONS(r1,kv[1]) ISS(r1,sv[4])
    CONS(r2,kv[2]) ISS(r2,sv[5])

    // gate-input prefetch under batch-flight cover
    const unsigned short* gp = gipre + ((size_t)t*1024 + bbase)*768;
    unsigned short gv[3][4];
    #pragma unroll
    for (int g3=0; g3<3; ++g3)
      #pragma unroll
      for (int q=0; q<4; ++q)
        gv[g3][q] = gp[(size_t)(lq4+q)*768 + g3*256 + col];
    if (t < 127){
      #pragma unroll
      for (int q=0; q<4; ++q)
        g_pre[q] = gamma[((size_t)(t+1)*1024 + bbase + lq4 + q)*256 + col];
    }
    __builtin_amdgcn_sched_barrier(0);

    CONS(r0,kv[3])
    // LDS-resident ks4..5 (8 MFMA) — covers tail of batches 4,5
    #pragma unroll
    for (int ks2=0; ks2<2; ++ks2){
      u16x8 aL = *(const u16x8*)&hsw[(4+ks2)*512 + lane*8];
      #pragma unroll
      for (int g=0; g<4; ++g){
        u16x8 bL = *(const u16x8*)&Wlds[((w*8 + g*2 + ks2)*64 + lane)*8];
        acc[g] = mfma16(aL, bL, acc[g]);
      }
    }
    __builtin_amdgcn_sched_barrier(0);
    CONS(r1,kv[4])
    CONS(r2,kv[5])
    #undef ISS
    #undef CONS
    __syncthreads();   // S2: hsw reads done -> next phase1 may overwrite

    // ---- gate phase (in-register) ----
    #pragma unroll
    for (int q=0; q<4; ++q){
      float gr = bf2f(gv[0][q]);
      float gz = bf2f(gv[1][q]);
      float gn = bf2f(gv[2][q]);
      float rr = sigm(gr + acc[0][q]);
      float zz = sigm(gz + acc[1][q]);
      float nv = tanh_f(gn + acc[2][q] + rr*(acc[3][q] + bnn));
      float hn = (1.f-zz)*nv + zz*h_reg[q];
      h_reg[q] = hn;
      if (t == 127) out[(size_t)33554432 + (size_t)(bbase+lq4+q)*256 + col] = hn;
    }
  }
}

// ---- host glue -----------------------------------------------------------
extern "C" void kernel_launch(void* const* d_in, const int* in_sizes, int n_in,
                              void* d_out, int out_size, void* d_ws, size_t ws_size,
                              hipStream_t stream){
  (void)in_sizes; (void)n_in; (void)out_size; (void)ws_size;
  const float* X   = (const float*)d_in[0];
  const float* M   = (const float*)d_in[1];
  const float* D   = (const float*)d_in[2];
  const float* mu  = (const float*)d_in[3];
  const float* Xl  = (const float*)d_in[4];
  const float* Wdh = (const float*)d_in[5];
  const float* bdh = (const float*)d_in[6];
  const float* Wdx = (const float*)d_in[7];
  const float* bdx = (const float*)d_in[8];
  const float* Wih = (const float*)d_in[9];
  const float* Whh = (const float*)d_in[10];
  const float* bih = (const float*)d_in[11];
  const float* bhh = (const float*)d_in[12];
  float* out = (float*)d_out;
  char* ws = (char*)d_ws;

  // workspace layout
  unsigned short* gipre = (unsigned short*)ws;                      // 201326592 B
  unsigned short* gamma = (unsigned short*)(ws + 201326592);        //  67108864 B
  unsigned short* W2sw  = (unsigned short*)(ws + 268435456);        //    393216 B
  unsigned short* Wdsw  = (unsigned short*)(ws + 268828672);        //     65536 B
  unsigned short* WstrG = (unsigned short*)(ws + 268894208);        //    393216 B
  unsigned short* WldsG = (unsigned short*)(ws + 269287424);        //    131072 B
  float*          b2    = (float*)        (ws + 269418496);         //      3072 B
  // Apre (67.1MB) + Dt (33.6MB) staged inside d_out: fully consumed by the
  // GEMMs below BEFORE seq15 writes the real outputs (same-stream ordering).
  unsigned short* Apre = (unsigned short*)d_out;
  unsigned short* Dt   = (unsigned short*)((char*)d_out + 67108864);

  hipFuncSetAttribute(reinterpret_cast<const void*>(seq15),
                      hipFuncAttributeMaxDynamicSharedMemorySize, 139264);
  hipFuncSetAttribute(reinterpret_cast<const void*>(&gemm_lds<4,16,16,1>),
                      hipFuncAttributeMaxDynamicSharedMemorySize, 65536);
  hipFuncSetAttribute(reinterpret_cast<const void*>(&gemm_lds<8,48,8,0>),
                      hipFuncAttributeMaxDynamicSharedMemorySize, 65536);

  kw<<<256, 256, 0, stream>>>(Wdh, Wih, Whh, bih, bhh, WstrG, WldsG, W2sw, Wdsw, b2);
  kprep<<<1024, 256, 0, stream>>>(X, M, D, mu, Xl, Wdx, bdx, Apre, Dt);
  gemm_lds<4,16,16,1><<<1024, 512, 65536, stream>>>(Dt, Wdsw, bdh, gamma);
  gemm_lds<8,48,8,0><<<1024, 512, 65536, stream>>>(Apre, W2sw, b2, gipre);
  seq15<<<64, 1024, 139264, stream>>>(WstrG, WldsG, gamma, gipre, bhh, out);
}

// Round 19
// 909.465 us; speedup vs baseline: 1.3179x; 1.0337x over previous
//
#include <hip/hip_runtime.h>
#include <cstdint>
#include <cstddef>

typedef __attribute__((ext_vector_type(8))) __bf16 bf16x8;
typedef __attribute__((ext_vector_type(8))) unsigned short u16x8;
typedef __attribute__((ext_vector_type(4))) unsigned short u16x4;
typedef __attribute__((ext_vector_type(2))) unsigned short u16x2;
typedef __attribute__((ext_vector_type(4))) float f32x4;
typedef __attribute__((ext_vector_type(2))) float f32x2;

// ---- helpers -------------------------------------------------------------
__device__ __forceinline__ unsigned short f2bf(float f){
  unsigned int u = __float_as_uint(f);
  u += 0x7FFFu + ((u >> 16) & 1u);          // round to nearest even
  return (unsigned short)(u >> 16);
}
__device__ __forceinline__ float bf2f(unsigned short s){
  return __uint_as_float(((unsigned int)s) << 16);
}
__device__ __forceinline__ float sigm(float x){ return 1.f/(1.f + __expf(-x)); }
__device__ __forceinline__ float tanh_f(float x){ float e = __expf(2.f*x); return 1.f - 2.f/(e + 1.f); }
__device__ __forceinline__ f32x4 mfma16(u16x8 a, u16x8 b, f32x4 c){
  return __builtin_amdgcn_mfma_f32_16x16x32_bf16(
      __builtin_bit_cast(bf16x8, a), __builtin_bit_cast(bf16x8, b), c, 0, 0, 0);
}

// B=1024, T=128, F=128, H=256
// FINAL CONFIG = round 15 (best measured: 915.7us total, seq 735us).
// seq12: 64 WGs x 512 thr, 16 rows/WG. LDS-resident ks4..5 (128 KB);
// ks0..3,6,7 streamed 384 KB/step/CU through a 3-deep pipelined register
// rolling buffer (opaque-offset defeats LICM). At the measured per-CU
// stream ceiling of ~31 B/cy: 432 KB/step -> 5.8us/step. Verified at wall
// via three independent null probes (occupancy x2, nt-loads, XCD-stagger).

__device__ __forceinline__ float wcval(int g, int n, int k,
    const float* __restrict__ Wih, const float* __restrict__ Whh){
  if (g==0) return Wih[n*512 + 128+k]       + Whh[n*256 + k];
  if (g==1) return Wih[(256+n)*512 + 128+k] + Whh[(256+n)*256 + k];
  if (g==2) return Wih[(512+n)*512 + 128+k];
  return Whh[(512+n)*256 + k];
}

// ---- weight prep ---------------------------------------------------------
// WstrG: (((w*6+s)*8+i)*64+l)*8+j   s=0..5 -> ks_eff=[0,1,2,3,6,7][s],
//        g=i>>1, c=i&1, n=(w*2+c)*16+(l&15)   (196608 elems, 384 KB)
// WldsG: (((w*8+g*2+c)*2+ks2)*64+l)*8+j  ks=4+ks2 (65536 elems, 128 KB)
// W2  : [nt(48)][ks(8)][lane(64)][8] ; Wd : [nt(16)][ks(4)][lane(64)][8]
__global__ __launch_bounds__(256) void kw(
    const float* __restrict__ Wdh, const float* __restrict__ Wih,
    const float* __restrict__ Whh, const float* __restrict__ bih,
    const float* __restrict__ bhh,
    unsigned short* __restrict__ WstrG, unsigned short* __restrict__ WldsG,
    unsigned short* __restrict__ W2,
    unsigned short* __restrict__ Wd, float* __restrict__ b2){
  int i0 = blockIdx.x*256 + threadIdx.x;
  int stride = gridDim.x*256;
  for (int idx=i0; idx<196608; idx+=stride){          // WstrG (ks 0..3,6,7)
    int j=idx&7, l=(idx>>3)&63, r=idx>>9;             // r < 384
    int i=r&7, r2=r>>3;                               // r2 = w*6+s
    int s=r2%6, w=r2/6;
    int ks = (s<4) ? s : (s+2);
    int g=i>>1, c=i&1;
    int n = (w*2+c)*16 + (l&15);
    int k = ks*32 + ((l>>4)<<3) + j;
    WstrG[idx] = f2bf(wcval(g, n, k, Wih, Whh));
  }
  for (int idx=i0; idx<65536; idx+=stride){           // WldsG (ks 4..5)
    int j=idx&7, l=(idx>>3)&63, r=idx>>9;             // r < 128
    int ks2=r&1, r2=r>>1;
    int c=r2&1, g=(r2>>1)&3, w=r2>>3;
    int n = (w*2+c)*16 + (l&15);
    int k = (4+ks2)*32 + ((l>>4)<<3) + j;
    WldsG[idx] = f2bf(wcval(g, n, k, Wih, Whh));
  }
  for (int idx=i0; idx<196608; idx+=stride){
    int j=idx&7, l=(idx>>3)&63, ks=(idx>>9)&7, nt=idx>>12;
    int n = nt*16 + (l&15);
    int k = ks*32 + ((l>>4)<<3) + j;
    float v = (k<128) ? Wih[n*512 + k] : Wih[n*512 + 256 + k];
    W2[idx] = f2bf(v);
  }
  for (int idx=i0; idx<32768; idx+=stride){
    int j=idx&7, l=(idx>>3)&63, ks=(idx>>9)&3, nt=idx>>11;
    int n = nt*16 + (l&15);
    int k = ks*32 + ((l>>4)<<3) + j;
    Wd[idx] = f2bf(Wdh[n*128 + k]);
  }
  for (int idx=i0; idx<768; idx+=stride)
    b2[idx] = bih[idx] + (idx<512 ? bhh[idx] : 0.f);
}

// ---- elementwise prep (verified) -----------------------------------------
__global__ __launch_bounds__(256) void kprep(
    const float* __restrict__ X, const float* __restrict__ M,
    const float* __restrict__ D, const float* __restrict__ mu,
    const float* __restrict__ Xl, const float* __restrict__ Wdx,
    const float* __restrict__ bdx,
    unsigned short* __restrict__ Apre, unsigned short* __restrict__ Dt){
  int lane = threadIdx.x & 63;
  int wave = (blockIdx.x*256 + threadIdx.x) >> 6;
  int c0 = lane*2;
  float dg0 = Wdx[c0*128 + c0];
  float dg1 = Wdx[(c0+1)*128 + (c0+1)];
  float bx0 = bdx[c0], bx1 = bdx[c0+1];
  for (int r = wave; r < 131072; r += 4096){
    int t = r>>10, b = r&1023;
    size_t src = ((size_t)b*128 + t)*128 + c0;
    f32x2 x  = *(const f32x2*)(X+src);
    f32x2 m  = *(const f32x2*)(M+src);
    f32x2 d  = *(const f32x2*)(D+src);
    f32x2 xl = *(const f32x2*)(Xl+src);
    f32x2 mb = *(const f32x2*)(mu + b*128 + c0);
    float g0 = __expf(-fmaxf(0.f, d.x*dg0 + bx0));
    float g1 = __expf(-fmaxf(0.f, d.y*dg1 + bx1));
    float xh0 = g0*xl.x + (1.f-g0)*mb.x;
    float xh1 = g1*xl.y + (1.f-g1)*mb.y;
    float xi0 = m.x*x.x + (1.f-m.x)*xh0;
    float xi1 = m.y*x.y + (1.f-m.y)*xh1;
    size_t ar = (size_t)r*256;
    *(u16x2*)(Apre + ar + c0)        = u16x2{f2bf(xi0), f2bf(xi1)};
    *(u16x2*)(Apre + ar + 128 + c0)  = u16x2{f2bf(m.x), f2bf(m.y)};
    *(u16x2*)(Dt + (size_t)r*128 + c0) = u16x2{f2bf(d.x), f2bf(d.y)};
  }
}

// ---- LDS-staged activation GEMM (verified) -------------------------------
template<int KS, int NTOT, int PNT, int MODE>
__global__ __launch_bounds__(512) void gemm_lds(
    const unsigned short* __restrict__ A, const unsigned short* __restrict__ Bw,
    const float* __restrict__ bias, unsigned short* __restrict__ out){
  extern __shared__ char smem[];
  unsigned short* Bs = (unsigned short*)smem;       // 65536 B
  const int N = NTOT*16;
  const int lane = threadIdx.x & 63;
  const int w    = threadIdx.x >> 6;
  const size_t rb = (size_t)blockIdx.x*128 + w*16;
  const int lr = lane&15, lk=(lane>>4)<<3, lq=(lane>>4)<<2;
  u16x8 a[KS];
  #pragma unroll
  for (int ks=0; ks<KS; ++ks)
    a[ks] = *(const u16x8*)&A[(rb + lr)*(KS*32) + ks*32 + lk];
  #pragma unroll
  for (int p=0; p<NTOT/PNT; ++p){
    __syncthreads();
    {
      const u16x8* src = (const u16x8*)&Bw[(size_t)p*PNT*KS*512];
      u16x8* dst = (u16x8*)Bs;
      #pragma unroll
      for (int i=0; i<8; ++i)
        dst[threadIdx.x + i*512] = src[threadIdx.x + i*512];
    }
    __syncthreads();
    f32x4 acc[PNT];
    #pragma unroll
    for (int i=0; i<PNT; ++i) acc[i] = f32x4{0.f,0.f,0.f,0.f};
    #pragma unroll
    for (int ks=0; ks<KS; ++ks)
      #pragma unroll
      for (int i=0; i<PNT; ++i){
        u16x8 b = *(const u16x8*)&Bs[((i*KS + ks)*64 + lane)*8];
        acc[i] = mfma16(a[ks], b, acc[i]);
      }
    #pragma unroll
    for (int i=0; i<PNT; ++i){
      int col = (p*PNT + i)*16 + lr;
      float bv = bias[col];
      #pragma unroll
      for (int q=0; q<4; ++q){
        float v = acc[i][q] + bv;
        if (MODE==1) v = __expf(-fmaxf(0.f, v));
        out[(rb + lq + q)*(size_t)N + col] = f2bf(v);
      }
    }
  }
}

// ---- persistent sequential kernel (round-14/15 verified, best) -----------
__global__ __launch_bounds__(512)
__attribute__((amdgpu_waves_per_eu(2, 2)))
void seq12(
    const unsigned short* __restrict__ WstrG, const unsigned short* __restrict__ WldsG,
    const unsigned short* __restrict__ gamma, const unsigned short* __restrict__ gipre,
    const float* __restrict__ bhh, float* __restrict__ out){
  extern __shared__ char smem[];
  unsigned short* Wlds = (unsigned short*)smem;            // 131072 B (ks4,5)
  unsigned short* hsw  = (unsigned short*)(smem + 131072); //   8192 B
  const int tid  = threadIdx.x;
  const int lane = tid & 63;
  const int w    = tid >> 6;              // 0..7
  const int bbase = blockIdx.x * 16;
  const int lr   = lane & 15;
  const int lq4  = (lane >> 4) << 2;

  for (int i = tid; i < 8192; i += 512)
    *(u16x8*)&Wlds[i*8] = *(const u16x8*)&WldsG[i*8];

  float h_reg[2][4];
  #pragma unroll
  for (int c=0; c<2; ++c)
    #pragma unroll
    for (int q=0; q<4; ++q) h_reg[c][q] = 0.f;

  float bnv[2];
  #pragma unroll
  for (int c=0; c<2; ++c) bnv[c] = bhh[512 + w*32 + c*16 + lr];

  unsigned short g_pre[2][4];
  #pragma unroll
  for (int c=0; c<2; ++c)
    #pragma unroll
    for (int q=0; q<4; ++q)
      g_pre[c][q] = gamma[((size_t)(bbase + lq4 + q))*256 + w*32 + c*16 + lr];

  const unsigned short* wsb = WstrG + (size_t)w*24576 + lane*8;

  __syncthreads();

  for (int t = 0; t < 128; ++t){
    #pragma unroll
    for (int c=0; c<2; ++c){
      const int col = w*32 + c*16 + lr;
      #pragma unroll
      for (int q=0; q<4; ++q){
        float hd = h_reg[c][q] * bf2f(g_pre[c][q]);
        h_reg[c][q] = hd;
        hsw[(col>>5)*512 + ((lq4+q) + (((col>>3)&3)<<4))*8 + (col&7)] = f2bf(hd);
      }
    }
    __syncthreads();   // S1: hsw ready

    #pragma unroll
    for (int c=0; c<2; ++c){
      const int col = w*32 + c*16 + lr;
      #pragma unroll
      for (int q=0; q<4; ++q)
        out[((size_t)(bbase+lq4+q)*128 + t)*256 + col] = h_reg[c][q];
    }

    f32x4 acc[4][2];
    #pragma unroll
    for (int g=0; g<4; ++g)
      #pragma unroll
      for (int c=0; c<2; ++c) acc[g][c] = f32x4{0.f,0.f,0.f,0.f};

    int off = 0;
    asm volatile("" : "+v"(off));
    const unsigned short* wp = wsb + off;

    u16x8 r0[8], r1[8], r2[8];
    #define ISS(r_, s_) { \
      _Pragma("unroll") \
      for (int i=0;i<8;++i) r_[i] = *(const u16x8*)(wp + ((s_)*8+i)*512); \
      } __builtin_amdgcn_sched_barrier(0);
    #define CONS(r_, ks_) { \
      u16x8 aR = *(const u16x8*)&hsw[(ks_)*512 + lane*8]; \
      _Pragma("unroll") \
      for (int i=0;i<8;++i) acc[i>>1][i&1] = mfma16(aR, r_[i], acc[i>>1][i&1]); \
      } __builtin_amdgcn_sched_barrier(0);

    ISS(r0,0) ISS(r1,1) ISS(r2,2)
    CONS(r0,0) ISS(r0,3)
    CONS(r1,1) ISS(r1,4)
    CONS(r2,2) ISS(r2,5)

    const unsigned short* gp = gipre + ((size_t)t*1024 + bbase)*768;
    unsigned short gv[3][2][4];
    #pragma unroll
    for (int g3=0; g3<3; ++g3)
      #pragma unroll
      for (int c=0; c<2; ++c)
        #pragma unroll
        for (int q=0; q<4; ++q)
          gv[g3][c][q] = gp[(size_t)(lq4+q)*768 + g3*256 + w*32 + c*16 + lr];
    if (t < 127){
      #pragma unroll
      for (int c=0; c<2; ++c)
        #pragma unroll
        for (int q=0; q<4; ++q)
          g_pre[c][q] = gamma[((size_t)(t+1)*1024 + bbase + lq4 + q)*256 + w*32 + c*16 + lr];
    }
    __builtin_amdgcn_sched_barrier(0);

    CONS(r0,3)
    #pragma unroll
    for (int ks2=0; ks2<2; ++ks2){
      u16x8 aL = *(const u16x8*)&hsw[(4+ks2)*512 + lane*8];
      #pragma unroll
      for (int g=0; g<4; ++g)
        #pragma unroll
        for (int c=0; c<2; ++c){
          u16x8 bL = *(const u16x8*)&Wlds[((w*8+g*2+c)*2 + ks2)*512 + lane*8];
          acc[g][c] = mfma16(aL, bL, acc[g][c]);
        }
    }
    __builtin_amdgcn_sched_barrier(0);
    CONS(r1,6)
    CONS(r2,7)
    #undef ISS
    #undef CONS
    __syncthreads();   // S2

    #pragma unroll
    for (int c=0; c<2; ++c){
      const int col = w*32 + c*16 + lr;
      #pragma unroll
      for (int q=0; q<4; ++q){
        float gr = bf2f(gv[0][c][q]);
        float gz = bf2f(gv[1][c][q]);
        float gn = bf2f(gv[2][c][q]);
        float rr = sigm(gr + acc[0][c][q]);
        float zz = sigm(gz + acc[1][c][q]);
        float nv = tanh_f(gn + acc[2][c][q] + rr*(acc[3][c][q] + bnv[c]));
        float hn = (1.f-zz)*nv + zz*h_reg[c][q];
        h_reg[c][q] = hn;
        if (t == 127) out[(size_t)33554432 + (size_t)(bbase+lq4+q)*256 + col] = hn;
      }
    }
  }
}

// ---- host glue -----------------------------------------------------------
extern "C" void kernel_launch(void* const* d_in, const int* in_sizes, int n_in,
                              void* d_out, int out_size, void* d_ws, size_t ws_size,
                              hipStream_t stream){
  (void)in_sizes; (void)n_in; (void)out_size; (void)ws_size;
  const float* X   = (const float*)d_in[0];
  const float* M   = (const float*)d_in[1];
  const float* D   = (const float*)d_in[2];
  const float* mu  = (const float*)d_in[3];
  const float* Xl  = (const float*)d_in[4];
  const float* Wdh = (const float*)d_in[5];
  const float* bdh = (const float*)d_in[6];
  const float* Wdx = (const float*)d_in[7];
  const float* bdx = (const float*)d_in[8];
  const float* Wih = (const float*)d_in[9];
  const float* Whh = (const float*)d_in[10];
  const float* bih = (const float*)d_in[11];
  const float* bhh = (const float*)d_in[12];
  float* out = (float*)d_out;
  char* ws = (char*)d_ws;

  // workspace layout
  unsigned short* gipre = (unsigned short*)ws;                      // 201326592 B
  unsigned short* gamma = (unsigned short*)(ws + 201326592);        //  67108864 B
  unsigned short* W2sw  = (unsigned short*)(ws + 268435456);        //    393216 B
  unsigned short* Wdsw  = (unsigned short*)(ws + 268828672);        //     65536 B
  unsigned short* WstrG = (unsigned short*)(ws + 268894208);        //    393216 B
  unsigned short* WldsG = (unsigned short*)(ws + 269287424);        //    131072 B
  float*          b2    = (float*)        (ws + 269418496);         //      3072 B
  // Apre (67.1MB) + Dt (33.6MB) staged inside d_out: fully consumed by the
  // GEMMs below BEFORE seq12 writes the real outputs (same-stream ordering).
  unsigned short* Apre = (unsigned short*)d_out;
  unsigned short* Dt   = (unsigned short*)((char*)d_out + 67108864);

  hipFuncSetAttribute(reinterpret_cast<const void*>(seq12),
                      hipFuncAttributeMaxDynamicSharedMemorySize, 139264);
  hipFuncSetAttribute(reinterpret_cast<const void*>(&gemm_lds<4,16,16,1>),
                      hipFuncAttributeMaxDynamicSharedMemorySize, 65536);
  hipFuncSetAttribute(reinterpret_cast<const void*>(&gemm_lds<8,48,8,0>),
                      hipFuncAttributeMaxDynamicSharedMemorySize, 65536);

  kw<<<256, 256, 0, stream>>>(Wdh, Wih, Whh, bih, bhh, WstrG, WldsG, W2sw, Wdsw, b2);
  kprep<<<1024, 256, 0, stream>>>(X, M, D, mu, Xl, Wdx, bdx, Apre, Dt);
  gemm_lds<4,16,16,1><<<1024, 512, 65536, stream>>>(Dt, Wdsw, bdh, gamma);
  gemm_lds<8,48,8,0><<<1024, 512, 65536, stream>>>(Apre, W2sw, b2, gipre);
  seq12<<<64, 512, 139264, stream>>>(WstrG, WldsG, gamma, gipre, bhh, out);
}